// Round 9
// baseline (119.502 us; speedup 1.0000x reference)
//
#include <hip/hip_runtime.h>
#include <hip/hip_bf16.h>
#include <math.h>

// ---------------------------------------------------------------------------
// GatedTinyMambaLayer: B=8, T=2048, DM=1024, DS=256
// s_prev = broadcast(prev_state) -> per-batch [8,256] precomputes.
// Pipeline (4 launches): prep_all (cvt_x + weight prep + state GEMVs) ->
// gemm1sg (128x96 tile, counted-vmcnt 3-stage pipeline, epilogue computes
// S,G; no Y) -> gemm2h -> gemm3.
// wcat row order: 8 groups of 96 rows: group g = {W_in+W_x[g*32..+31],
// W_gx[g*32..+31], W_dc[g*32..+31]}.
// ---------------------------------------------------------------------------

typedef __attribute__((ext_vector_type(4)))  float f32x4;
typedef __attribute__((ext_vector_type(8)))  short bf16x8;

#define DEV static __device__ __forceinline__

DEV float bf2f(short u) {
  union { float f; unsigned i; } v; v.i = ((unsigned)(unsigned short)u) << 16; return v.f;
}
DEV short f2bf(float f) {  // round-to-nearest-even
  union { float f; unsigned i; } v; v.f = f;
  unsigned x = v.i;
  return (short)((x + 0x7fffu + ((x >> 16) & 1u)) >> 16);
}
DEV unsigned pk_bf16(float lo, float hi) {  // -> v_cvt_pk_bf16_f32
  __hip_bfloat162 h = __float22bfloat162_rn(make_float2(lo, hi));
  return *(unsigned*)&h;
}
DEV float sigmoidf_(float x) { return 1.f / (1.f + expf(-x)); }

DEV void gl16(const void* g, void* l) {
  __builtin_amdgcn_global_load_lds(
      (const __attribute__((address_space(1))) void*)(g),
      (__attribute__((address_space(3))) void*)(l), 16, 0, 0);
}

// stage one 128x32 bf16 subtile pair into linear LDS [128][32] via gload_lds
DEV void stage_tile(const short* gA, const short* gB, short* As, short* Bs,
                    int lda, int ldb, int w, int lane) {
  const int rsub = lane >> 2, kc = (lane & 3) * 8;
#pragma unroll
  for (int j = 0; j < 2; ++j) {
    const int seg = w * 2 + j;           // 0..7, 16 rows each
    const int r = seg * 16 + rsub;
    gl16(gA + (size_t)r * lda + kc, As + seg * 512);
    gl16(gB + (size_t)r * ldb + kc, Bs + seg * 512);
  }
}

DEV void kstep(const short* Asb, const short* Bsb, int wr, int wc, int arow, int ag,
               f32x4 (&acc)[4][4]) {
  bf16x8 af[4], bfv[4];
#pragma unroll
  for (int mi = 0; mi < 4; ++mi)
    af[mi] = *(const bf16x8*)(Asb + (wr * 64 + mi * 16 + arow) * 32 + ag * 8);
#pragma unroll
  for (int ni = 0; ni < 4; ++ni)
    bfv[ni] = *(const bf16x8*)(Bsb + (wc * 64 + ni * 16 + arow) * 32 + ag * 8);
#pragma unroll
  for (int mi = 0; mi < 4; ++mi)
#pragma unroll
    for (int ni = 0; ni < 4; ++ni)
      acc[mi][ni] = __builtin_amdgcn_mfma_f32_16x16x32_bf16(af[mi], bfv[ni], acc[mi][ni], 0, 0, 0);
}

// ---- workspace layout (bytes) ---------------------------------------------
static const size_t OFF_S    = 0;                   // bf16 [16384][256]
static const size_t OFF_G    = 8388608;             // bf16 [16384][256]
static const size_t OFF_XBF  = 25165824;            // bf16 [16384][1024]; H aliases (dead after gemm1)
static const size_t OFF_WCAT = OFF_XBF + 33554432;  // bf16 [768][1024] (96-row groups)
static const size_t OFF_WPP  = OFF_WCAT + 1572864;  // bf16 [256][256]  (W_pp[:, :256])
static const size_t OFF_WOUT = OFF_WPP + 131072;    // bf16 [1024][256]
static const size_t OFF_VEC  = OFF_WOUT + 524288;   // f32 [5][2048]: sdc,sws,spp,pstr,gst

// ---------------------------------------------------------------------------
// prep_all: blocks [0,8192) cvt_x ; [8192,12544) prep_w ; [12544,12704) state
__global__ __launch_bounds__(256, 1) void prep_all_k(
    const float* __restrict__ x, short* __restrict__ xbf,
    const float* __restrict__ W_in, const float* __restrict__ W_x,
    const float* __restrict__ W_gx, const float* __restrict__ W_dc,
    const float* __restrict__ W_pp, const float* __restrict__ W_out,
    short* __restrict__ wcat, short* __restrict__ wpp, short* __restrict__ wout,
    const float* __restrict__ prev, const float* __restrict__ Ws,
    const float* __restrict__ bdc, const float* __restrict__ bpp,
    const float* __restrict__ Wpg, const float* __restrict__ bpg,
    const float* __restrict__ Wgs, const float* __restrict__ bgs,
    float* __restrict__ vecs) {
  const int bid = (int)blockIdx.x, tid = (int)threadIdx.x;
  if (bid < 8192) {  // ---- x f32 -> bf16, 8 elems/thread
    const size_t i = ((size_t)bid * 256 + tid) * 8;
    const float4 a = *(const float4*)(x + i);
    const float4 b = *(const float4*)(x + i + 4);
    uint4 o;
    o.x = pk_bf16(a.x, a.y); o.y = pk_bf16(a.z, a.w);
    o.z = pk_bf16(b.x, b.y); o.w = pk_bf16(b.z, b.w);
    *(uint4*)(xbf + i) = o;
  } else if (bid < 12544) {  // ---- weight prep
    const int idx = (bid - 8192) * 256 + tid;
    const int N_WCAT = 768 * 1024, N_WPP = 256 * 256;
    if (idx < N_WCAT) {
      const int r = idx >> 10, k = idx & 1023;
      const int g = r / 96, j = r % 96;
      float v;
      if (j < 32)      v = W_in[(g * 32 + j) * 1024 + k] + W_x[(g * 32 + j) * 1024 + k];
      else if (j < 64) v = W_gx[(g * 32 + j - 32) * 1024 + k];
      else             v = W_dc[(g * 32 + j - 64) * 1280 + k];
      wcat[idx] = f2bf(v);
    } else if (idx < N_WCAT + N_WPP) {
      const int j = idx - N_WCAT, o = j >> 8, k = j & 255;
      wpp[j] = f2bf(W_pp[o * 512 + k]);          // W_pp[:, :256]
    } else {
      const int j = idx - N_WCAT - N_WPP, o = j >> 8, k = j & 255;
      wout[j] = f2bf(W_out[o * 256 + k]);
    }
  } else {  // ---- per-batch state GEMVs (coalesced, butterfly reduce)
    const int sb = bid - 12544;
    const int b = sb / 20, rem = sb % 20, m = rem >> 2, oq = rem & 3;
    const int lane = tid & 63, w = tid >> 6;
    const float4 sv = *(const float4*)(prev + b * 256 + lane * 4);
    const float* Wb; const float* bias; int stride, off;
    if (m == 0)      { Wb = W_dc; stride = 1280; off = 1024; bias = bdc; }
    else if (m == 1) { Wb = Ws;   stride = 256;  off = 0;    bias = nullptr; }
    else if (m == 2) { Wb = W_pp; stride = 512;  off = 256;  bias = bpp; }
    else if (m == 3) { Wb = Wpg;  stride = 256;  off = 0;    bias = bpg; }
    else             { Wb = Wgs;  stride = 256;  off = 0;    bias = bgs; }
    const int o0 = oq * 64 + w * 16;
#pragma unroll 4
    for (int i = 0; i < 16; ++i) {
      const int o = o0 + i;
      const float4 wv = *(const float4*)(Wb + (size_t)o * stride + off + lane * 4);
      float p = wv.x * sv.x + wv.y * sv.y + wv.z * sv.z + wv.w * sv.w;
#pragma unroll
      for (int d = 32; d >= 1; d >>= 1) p += __shfl_xor(p, d, 64);
      if (lane == 0) {
        float r = (m == 1) ? 0.5f * p : p + bias[o];
        if (m >= 3) r = sigmoidf_(r);
        vecs[m * 2048 + b * 256 + o] = r;
      }
    }
  }
}

// ---------------------------------------------------------------------------
// GEMM1+SG: 128x96 tile, grid = 128 m-tiles x 8 col-groups = 1024 blocks.
// Counted-vmcnt 3-stage pipeline: stage(t+2) issued, then s_waitcnt vmcnt(8)
// (waits only this wave's stage(t); 8 newer loads stay in flight across the
// barrier) + raw s_barrier. Uniform 4 gl16/thread/stage (B padded to 128
// staged rows, 96 consumed; overread past wcat lands in wpp - valid).
// Epilogue: S = prev*exp(-.05*sig(dc+sdc)) + ix + sws ; G = sig(gx+bgx).
__global__ __launch_bounds__(256) void gemm1sg_k(const short* __restrict__ A,
                                                 const short* __restrict__ Bm,
                                                 const float* __restrict__ prev,
                                                 const float* __restrict__ bgx,
                                                 const float* __restrict__ vecs,
                                                 short* __restrict__ S,
                                                 short* __restrict__ G) {
  __shared__ short As[3][4096];    // [128][32]
  __shared__ short Bs[3][4096];    // [128][32], rows 96..127 staged but unused
  const int tid = (int)threadIdx.x, lane = tid & 63, w = tid >> 6;
  int bid = (int)blockIdx.x;
  bid = (bid & 7) * 128 + (bid >> 3);          // XCD swizzle (1024 % 8 == 0)
  const int mt = bid >> 3, ntg = bid & 7;
  const int m0 = mt * 128, b = m0 >> 11;
  const short* gA = A + (size_t)m0 * 1024;
  const short* gB = Bm + (size_t)(ntg * 96) * 1024;
  const int rsub = lane >> 2, kc = (lane & 3) * 8;

  f32x4 acc[2][6];
#pragma unroll
  for (int mi = 0; mi < 2; ++mi)
#pragma unroll
    for (int ni = 0; ni < 6; ++ni)
#pragma unroll
      for (int r = 0; r < 4; ++r) acc[mi][ni][r] = 0.f;

  // uniform stage: 2 A-segs + 2 B-segs per thread = 4 gl16 (issue order fixed)
#define STAGE(s, t)                                                           \
  {                                                                           \
    _Pragma("unroll")                                                         \
    for (int j = 0; j < 2; ++j) {                                             \
      const int seg = w * 2 + j;                                              \
      const size_t roff = (size_t)(seg * 16 + rsub) * 1024 + (size_t)(t) * 32 + kc; \
      gl16(gA + roff, As[s] + seg * 512);                                     \
      gl16(gB + roff, Bs[s] + seg * 512);                                     \
    }                                                                         \
  }

  STAGE(0, 0);
  STAGE(1, 1);
  const int arow = lane & 15, ag = lane >> 4;
  int cur = 0;
#pragma unroll 1
  for (int t = 0; t < 32; ++t) {
    int pre = cur + 2; if (pre >= 3) pre -= 3;
    if (t < 30) {
      STAGE(pre, t + 2);
      asm volatile("s_waitcnt vmcnt(8)" ::: "memory");
    } else if (t == 30) {
      asm volatile("s_waitcnt vmcnt(4)" ::: "memory");
    } else {
      asm volatile("s_waitcnt vmcnt(0)" ::: "memory");
    }
    __builtin_amdgcn_s_barrier();
    __builtin_amdgcn_sched_barrier(0);
    const short* Asb = As[cur];
    const short* Bsb = Bs[cur];
    bf16x8 af[2];
#pragma unroll
    for (int mi = 0; mi < 2; ++mi)
      af[mi] = *(const bf16x8*)(Asb + (w * 32 + mi * 16 + arow) * 32 + ag * 8);
#pragma unroll
    for (int ni = 0; ni < 6; ++ni) {
      const bf16x8 bf = *(const bf16x8*)(Bsb + (ni * 16 + arow) * 32 + ag * 8);
#pragma unroll
      for (int mi = 0; mi < 2; ++mi)
        acc[mi][ni] = __builtin_amdgcn_mfma_f32_16x16x32_bf16(af[mi], bf, acc[mi][ni], 0, 0, 0);
    }
    __builtin_amdgcn_s_barrier();   // protect buffer reuse by next STAGE
    cur = (cur == 2) ? 0 : cur + 1;
  }
#undef STAGE

  // epilogue: B-rows 0..31 = ix, 32..63 = gx, 64..95 = dc (within group ntg)
  const int quad = lane >> 4;
#pragma unroll
  for (int nj = 0; nj < 2; ++nj) {
    const int cg = ntg * 32 + nj * 16 + arow;
    const float sdc = vecs[0 * 2048 + b * 256 + cg];
    const float sws = vecs[1 * 2048 + b * 256 + cg];
    const float pv  = prev[b * 256 + cg];
    const float bg  = bgx[cg];
#pragma unroll
    for (int mi = 0; mi < 2; ++mi)
#pragma unroll
      for (int r = 0; r < 4; ++r) {
        const int row = m0 + w * 32 + mi * 16 + quad * 4 + r;
        const float dec = expf(-0.05f * sigmoidf_(acc[mi][4 + nj][r] + sdc));
        const float sp = pv * dec + acc[mi][nj][r] + sws;
        const float g = sigmoidf_(acc[mi][2 + nj][r] + bg);
        S[(size_t)row * 256 + cg] = f2bf(sp);
        G[(size_t)row * 256 + cg] = f2bf(g);
      }
  }
}

// ---------------------------------------------------------------------------
// GEMM2 + elementwise: P = S @ wpp^T; h = (S + pstr*tanh(P+spp)) * G * gst
__global__ __launch_bounds__(256) void gemm2h_k(const short* __restrict__ S,
                                                const short* __restrict__ G,
                                                const short* __restrict__ Wpp,
                                                const float* __restrict__ vecs,
                                                short* __restrict__ H,
                                                float* __restrict__ out) {
  __shared__ short As[2][4096];
  __shared__ short Bs[2][4096];
  const int tid = (int)threadIdx.x, lane = tid & 63, w = tid >> 6;
  const int wr = w >> 1, wc = w & 1;
  int bid = (int)blockIdx.x;
  bid = (bid & 7) * 32 + (bid >> 3);           // 256 % 8 == 0
  const int m0 = (bid >> 1) * 128, n0 = (bid & 1) * 128;
  const int b = m0 >> 11;
  const short* gA = S + (size_t)m0 * 256;
  const short* gB = Wpp + (size_t)n0 * 256;

  f32x4 acc[4][4];
#pragma unroll
  for (int mi = 0; mi < 4; ++mi)
#pragma unroll
    for (int ni = 0; ni < 4; ++ni)
#pragma unroll
      for (int r = 0; r < 4; ++r) acc[mi][ni][r] = 0.f;

  stage_tile(gA, gB, As[0], Bs[0], 256, 256, w, lane);
  __syncthreads();
  const int arow = lane & 15, ag = lane >> 4;
#pragma unroll 1
  for (int t = 0; t < 8; ++t) {
    if (t < 7)
      stage_tile(gA + (t + 1) * 32, gB + (t + 1) * 32,
                 As[(t + 1) & 1], Bs[(t + 1) & 1], 256, 256, w, lane);
    kstep(As[t & 1], Bs[t & 1], wr, wc, arow, ag, acc);
    __syncthreads();
  }
#pragma unroll
  for (int mi = 0; mi < 4; ++mi)
#pragma unroll
    for (int ni = 0; ni < 4; ++ni) {
      const int col = n0 + wc * 64 + ni * 16 + (lane & 15);
      const float spp  = vecs[2 * 2048 + b * 256 + col];
      const float pstr = vecs[3 * 2048 + b * 256 + col];
      const float gst  = vecs[4 * 2048 + b * 256 + col];
#pragma unroll
      for (int r = 0; r < 4; ++r) {
        const int row = m0 + wr * 64 + mi * 16 + (lane >> 4) * 4 + r;
        const float pv = tanhf(acc[mi][ni][r] + spp);
        const float sp = bf2f(S[(size_t)row * 256 + col]);
        const float h = (sp + pstr * pv) * bf2f(G[(size_t)row * 256 + col]) * gst;
        H[(size_t)row * 256 + col] = f2bf(h);
        if ((row & 2047) == 2047) out[16777216 + b * 256 + col] = h;
      }
    }
}

// ---------------------------------------------------------------------------
// GEMM3: out[16384][1024] f32 = H @ wout^T. K=256 -> 8 k-steps. (m97 form)
__global__ __launch_bounds__(256) void gemm3_k(const short* __restrict__ H,
                                               const short* __restrict__ Wout,
                                               float* __restrict__ out) {
  __shared__ short As[2][4096];
  __shared__ short Bs[2][4096];
  const int tid = (int)threadIdx.x, lane = tid & 63, w = tid >> 6;
  const int wr = w >> 1, wc = w & 1;
  int bid = (int)blockIdx.x;
  bid = (bid & 7) * 128 + (bid >> 3);          // 1024 % 8 == 0
  const int m0 = (bid >> 3) * 128, n0 = (bid & 7) * 128;
  const short* gA = H + (size_t)m0 * 256;
  const short* gB = Wout + (size_t)n0 * 256;

  f32x4 acc[4][4];
#pragma unroll
  for (int mi = 0; mi < 4; ++mi)
#pragma unroll
    for (int ni = 0; ni < 4; ++ni)
#pragma unroll
      for (int r = 0; r < 4; ++r) acc[mi][ni][r] = 0.f;

  stage_tile(gA, gB, As[0], Bs[0], 256, 256, w, lane);
  __syncthreads();
  const int arow = lane & 15, ag = lane >> 4;
#pragma unroll 1
  for (int t = 0; t < 8; ++t) {
    if (t < 7)
      stage_tile(gA + (t + 1) * 32, gB + (t + 1) * 32,
                 As[(t + 1) & 1], Bs[(t + 1) & 1], 256, 256, w, lane);
    kstep(As[t & 1], Bs[t & 1], wr, wc, arow, ag, acc);
    __syncthreads();
  }
#pragma unroll
  for (int mi = 0; mi < 4; ++mi)
#pragma unroll
    for (int ni = 0; ni < 4; ++ni) {
      const int col = n0 + wc * 64 + ni * 16 + (lane & 15);
#pragma unroll
      for (int r = 0; r < 4; ++r) {
        const int row = m0 + wr * 64 + mi * 16 + (lane >> 4) * 4 + r;
        out[(size_t)row * 1024 + col] = acc[mi][ni][r];
      }
    }
}

// ---------------------------------------------------------------------------
extern "C" void kernel_launch(void* const* d_in, const int* in_sizes, int n_in,
                              void* d_out, int out_size, void* d_ws, size_t ws_size,
                              hipStream_t stream) {
  (void)in_sizes; (void)n_in; (void)out_size; (void)ws_size;
  const float* x      = (const float*)d_in[0];
  const float* prev   = (const float*)d_in[1];
  const float* W_in   = (const float*)d_in[2];
  const float* W_x    = (const float*)d_in[3];
  const float* W_s    = (const float*)d_in[4];
  const float* W_out  = (const float*)d_in[5];
  const float* W_gx   = (const float*)d_in[6];
  const float* b_gx   = (const float*)d_in[7];
  const float* W_gs   = (const float*)d_in[8];
  const float* b_gs   = (const float*)d_in[9];
  const float* W_dc   = (const float*)d_in[10];
  const float* b_dc   = (const float*)d_in[11];
  const float* W_pp   = (const float*)d_in[12];
  const float* b_pp   = (const float*)d_in[13];
  const float* W_pg   = (const float*)d_in[14];
  const float* b_pg   = (const float*)d_in[15];

  char* ws = (char*)d_ws;
  short* S    = (short*)(ws + OFF_S);
  short* G    = (short*)(ws + OFF_G);
  short* xbf  = (short*)(ws + OFF_XBF);
  short* H    = (short*)(ws + OFF_XBF);   // aliases xbf (dead after gemm1)
  short* wcat = (short*)(ws + OFF_WCAT);
  short* wpp  = (short*)(ws + OFF_WPP);
  short* wout = (short*)(ws + OFF_WOUT);
  float* vecs = (float*)(ws + OFF_VEC);
  float* out  = (float*)d_out;

  prep_all_k<<<12704, 256, 0, stream>>>(x, xbf, W_in, W_x, W_gx, W_dc, W_pp, W_out,
                                        wcat, wpp, wout, prev, W_s, b_dc, b_pp,
                                        W_pg, b_pg, W_gs, b_gs, vecs);
  gemm1sg_k<<<1024, 256, 0, stream>>>(xbf, wcat, prev, b_gx, vecs, S, G);
  gemm2h_k<<<256, 256, 0, stream>>>(S, G, wpp, vecs, H, out);
  gemm3_k<<<1024, 256, 0, stream>>>(H, wout, out);
}

// Round 10
// 110.454 us; speedup vs baseline: 1.0819x; 1.0819x over previous
//
#include <hip/hip_runtime.h>
#include <hip/hip_bf16.h>
#include <math.h>

// ---------------------------------------------------------------------------
// GatedTinyMambaLayer: B=8, T=2048, DM=1024, DS=256
// s_prev = broadcast(prev_state) -> per-batch [8,256] precomputes.
// Pipeline (4 launches): prep_all (cvt_x + weight prep + state GEMVs) ->
// gemm1sg (128x96 tile, m97 single-barrier dbuf loop; epilogue computes S,G)
// -> gemm2h -> gemm3 (128x256 tile).
// wcat row order: 8 groups of 96 rows: group g = {W_in+W_x[g*32..+31],
// W_gx[g*32..+31], W_dc[g*32..+31]}.
// ---------------------------------------------------------------------------

typedef __attribute__((ext_vector_type(4)))  float f32x4;
typedef __attribute__((ext_vector_type(8)))  short bf16x8;

#define DEV static __device__ __forceinline__

DEV float bf2f(short u) {
  union { float f; unsigned i; } v; v.i = ((unsigned)(unsigned short)u) << 16; return v.f;
}
DEV short f2bf(float f) {  // round-to-nearest-even
  union { float f; unsigned i; } v; v.f = f;
  unsigned x = v.i;
  return (short)((x + 0x7fffu + ((x >> 16) & 1u)) >> 16);
}
DEV unsigned pk_bf16(float lo, float hi) {  // -> v_cvt_pk_bf16_f32
  __hip_bfloat162 h = __float22bfloat162_rn(make_float2(lo, hi));
  return *(unsigned*)&h;
}
DEV float sigmoidf_(float x) { return 1.f / (1.f + expf(-x)); }

DEV void gl16(const void* g, void* l) {
  __builtin_amdgcn_global_load_lds(
      (const __attribute__((address_space(1))) void*)(g),
      (__attribute__((address_space(3))) void*)(l), 16, 0, 0);
}

// stage one 128x32 bf16 subtile pair into linear LDS [128][32] via gload_lds
DEV void stage_tile(const short* gA, const short* gB, short* As, short* Bs,
                    int lda, int ldb, int w, int lane) {
  const int rsub = lane >> 2, kc = (lane & 3) * 8;
#pragma unroll
  for (int j = 0; j < 2; ++j) {
    const int seg = w * 2 + j;           // 0..7, 16 rows each
    const int r = seg * 16 + rsub;
    gl16(gA + (size_t)r * lda + kc, As + seg * 512);
    gl16(gB + (size_t)r * ldb + kc, Bs + seg * 512);
  }
}

DEV void kstep(const short* Asb, const short* Bsb, int wr, int wc, int arow, int ag,
               f32x4 (&acc)[4][4]) {
  bf16x8 af[4], bfv[4];
#pragma unroll
  for (int mi = 0; mi < 4; ++mi)
    af[mi] = *(const bf16x8*)(Asb + (wr * 64 + mi * 16 + arow) * 32 + ag * 8);
#pragma unroll
  for (int ni = 0; ni < 4; ++ni)
    bfv[ni] = *(const bf16x8*)(Bsb + (wc * 64 + ni * 16 + arow) * 32 + ag * 8);
#pragma unroll
  for (int mi = 0; mi < 4; ++mi)
#pragma unroll
    for (int ni = 0; ni < 4; ++ni)
      acc[mi][ni] = __builtin_amdgcn_mfma_f32_16x16x32_bf16(af[mi], bfv[ni], acc[mi][ni], 0, 0, 0);
}

// ---- workspace layout (bytes) ---------------------------------------------
static const size_t OFF_S    = 0;                   // bf16 [16384][256]
static const size_t OFF_G    = 8388608;             // bf16 [16384][256]
static const size_t OFF_XBF  = 25165824;            // bf16 [16384][1024]; H aliases (dead after gemm1)
static const size_t OFF_WCAT = OFF_XBF + 33554432;  // bf16 [768][1024] (96-row groups)
static const size_t OFF_WPP  = OFF_WCAT + 1572864;  // bf16 [256][256]  (W_pp[:, :256])
static const size_t OFF_WOUT = OFF_WPP + 131072;    // bf16 [1024][256]
static const size_t OFF_VEC  = OFF_WOUT + 524288;   // f32 [5][2048]: sdc,sws,spp,pstr,gst

// ---------------------------------------------------------------------------
// prep_all: blocks [0,8192) cvt_x ; [8192,12544) prep_w ; [12544,12704) state
__global__ __launch_bounds__(256, 1) void prep_all_k(
    const float* __restrict__ x, short* __restrict__ xbf,
    const float* __restrict__ W_in, const float* __restrict__ W_x,
    const float* __restrict__ W_gx, const float* __restrict__ W_dc,
    const float* __restrict__ W_pp, const float* __restrict__ W_out,
    short* __restrict__ wcat, short* __restrict__ wpp, short* __restrict__ wout,
    const float* __restrict__ prev, const float* __restrict__ Ws,
    const float* __restrict__ bdc, const float* __restrict__ bpp,
    const float* __restrict__ Wpg, const float* __restrict__ bpg,
    const float* __restrict__ Wgs, const float* __restrict__ bgs,
    float* __restrict__ vecs) {
  const int bid = (int)blockIdx.x, tid = (int)threadIdx.x;
  if (bid < 8192) {  // ---- x f32 -> bf16, 8 elems/thread
    const size_t i = ((size_t)bid * 256 + tid) * 8;
    const float4 a = *(const float4*)(x + i);
    const float4 b = *(const float4*)(x + i + 4);
    uint4 o;
    o.x = pk_bf16(a.x, a.y); o.y = pk_bf16(a.z, a.w);
    o.z = pk_bf16(b.x, b.y); o.w = pk_bf16(b.z, b.w);
    *(uint4*)(xbf + i) = o;
  } else if (bid < 12544) {  // ---- weight prep
    const int idx = (bid - 8192) * 256 + tid;
    const int N_WCAT = 768 * 1024, N_WPP = 256 * 256;
    if (idx < N_WCAT) {
      const int r = idx >> 10, k = idx & 1023;
      const int g = r / 96, j = r % 96;
      float v;
      if (j < 32)      v = W_in[(g * 32 + j) * 1024 + k] + W_x[(g * 32 + j) * 1024 + k];
      else if (j < 64) v = W_gx[(g * 32 + j - 32) * 1024 + k];
      else             v = W_dc[(g * 32 + j - 64) * 1280 + k];
      wcat[idx] = f2bf(v);
    } else if (idx < N_WCAT + N_WPP) {
      const int j = idx - N_WCAT, o = j >> 8, k = j & 255;
      wpp[j] = f2bf(W_pp[o * 512 + k]);          // W_pp[:, :256]
    } else {
      const int j = idx - N_WCAT - N_WPP, o = j >> 8, k = j & 255;
      wout[j] = f2bf(W_out[o * 256 + k]);
    }
  } else {  // ---- per-batch state GEMVs (coalesced, butterfly reduce)
    const int sb = bid - 12544;
    const int b = sb / 20, rem = sb % 20, m = rem >> 2, oq = rem & 3;
    const int lane = tid & 63, w = tid >> 6;
    const float4 sv = *(const float4*)(prev + b * 256 + lane * 4);
    const float* Wb; const float* bias; int stride, off;
    if (m == 0)      { Wb = W_dc; stride = 1280; off = 1024; bias = bdc; }
    else if (m == 1) { Wb = Ws;   stride = 256;  off = 0;    bias = nullptr; }
    else if (m == 2) { Wb = W_pp; stride = 512;  off = 256;  bias = bpp; }
    else if (m == 3) { Wb = Wpg;  stride = 256;  off = 0;    bias = bpg; }
    else             { Wb = Wgs;  stride = 256;  off = 0;    bias = bgs; }
    const int o0 = oq * 64 + w * 16;
#pragma unroll 4
    for (int i = 0; i < 16; ++i) {
      const int o = o0 + i;
      const float4 wv = *(const float4*)(Wb + (size_t)o * stride + off + lane * 4);
      float p = wv.x * sv.x + wv.y * sv.y + wv.z * sv.z + wv.w * sv.w;
#pragma unroll
      for (int d = 32; d >= 1; d >>= 1) p += __shfl_xor(p, d, 64);
      if (lane == 0) {
        float r = (m == 1) ? 0.5f * p : p + bias[o];
        if (m >= 3) r = sigmoidf_(r);
        vecs[m * 2048 + b * 256 + o] = r;
      }
    }
  }
}

// ---------------------------------------------------------------------------
// GEMM1+SG: 128x96 tile, grid = 128 m-tiles x 8 col-groups = 1024 blocks
// (4 blocks/CU). m97 single-barrier dbuf loop. 4 waves, each 32 rows x 96
// cols (acc[2][6]). K=1024.
// Epilogue: S = prev*exp(-.05*sig(dc+sdc)) + ix + sws ; G = sig(gx+bgx).
__global__ __launch_bounds__(256) void gemm1sg_k(const short* __restrict__ A,
                                                 const short* __restrict__ Bm,
                                                 const float* __restrict__ prev,
                                                 const float* __restrict__ bgx,
                                                 const float* __restrict__ vecs,
                                                 short* __restrict__ S,
                                                 short* __restrict__ G) {
  __shared__ short As[2][4096];    // [128][32]
  __shared__ short Bs[2][3072];    // [96][32]
  const int tid = (int)threadIdx.x, lane = tid & 63, w = tid >> 6;
  int bid = (int)blockIdx.x;
  bid = (bid & 7) * 128 + (bid >> 3);          // XCD swizzle (1024 % 8 == 0)
  const int mt = bid >> 3, ntg = bid & 7;
  const int m0 = mt * 128, b = m0 >> 11;
  const short* gA = A + (size_t)m0 * 1024;
  const short* gB = Bm + (size_t)(ntg * 96) * 1024;
  const int rsub = lane >> 2, kc = (lane & 3) * 8;

  f32x4 acc[2][6];
#pragma unroll
  for (int mi = 0; mi < 2; ++mi)
#pragma unroll
    for (int ni = 0; ni < 6; ++ni)
#pragma unroll
      for (int r = 0; r < 4; ++r) acc[mi][ni][r] = 0.f;

  // staging: A 512 granules (2/thread); B 384 granules (1/thread + half on w<2)
#define STAGE1(buf, t)                                                        \
  {                                                                           \
    _Pragma("unroll")                                                         \
    for (int j = 0; j < 2; ++j) {                                             \
      const int seg = w * 2 + j;                                              \
      gl16(gA + (size_t)(seg * 16 + rsub) * 1024 + (t) * 32 + kc,             \
           As[buf] + seg * 512);                                              \
    }                                                                         \
    {                                                                         \
      const int Gr = w * 64 + lane;                                           \
      gl16(gB + (size_t)(Gr >> 2) * 1024 + (t) * 32 + ((Gr & 3) * 8),         \
           Bs[buf] + w * 512);                                                \
    }                                                                         \
    if (w < 2) {                                                              \
      const int Gr = 256 + w * 64 + lane;                                     \
      gl16(gB + (size_t)(Gr >> 2) * 1024 + (t) * 32 + ((Gr & 3) * 8),         \
           Bs[buf] + 2048 + w * 512);                                         \
    }                                                                         \
  }

  STAGE1(0, 0);
  __syncthreads();
  const int arow = lane & 15, ag = lane >> 4;
#pragma unroll 1
  for (int t = 0; t < 32; ++t) {
    if (t < 31) STAGE1((t + 1) & 1, t + 1);
    const short* Asb = As[t & 1];
    const short* Bsb = Bs[t & 1];
    bf16x8 af[2];
#pragma unroll
    for (int mi = 0; mi < 2; ++mi)
      af[mi] = *(const bf16x8*)(Asb + (w * 32 + mi * 16 + arow) * 32 + ag * 8);
#pragma unroll
    for (int ni = 0; ni < 6; ++ni) {
      const bf16x8 bf = *(const bf16x8*)(Bsb + (ni * 16 + arow) * 32 + ag * 8);
#pragma unroll
      for (int mi = 0; mi < 2; ++mi)
        acc[mi][ni] = __builtin_amdgcn_mfma_f32_16x16x32_bf16(af[mi], bf, acc[mi][ni], 0, 0, 0);
    }
    __syncthreads();
  }
#undef STAGE1

  // epilogue: B-rows 0..31 = ix, 32..63 = gx, 64..95 = dc (within group ntg)
  const int quad = lane >> 4;
#pragma unroll
  for (int nj = 0; nj < 2; ++nj) {
    const int cg = ntg * 32 + nj * 16 + arow;
    const float sdc = vecs[0 * 2048 + b * 256 + cg];
    const float sws = vecs[1 * 2048 + b * 256 + cg];
    const float pv  = prev[b * 256 + cg];
    const float bg  = bgx[cg];
#pragma unroll
    for (int mi = 0; mi < 2; ++mi)
#pragma unroll
      for (int r = 0; r < 4; ++r) {
        const int row = m0 + w * 32 + mi * 16 + quad * 4 + r;
        const float dec = expf(-0.05f * sigmoidf_(acc[mi][4 + nj][r] + sdc));
        const float sp = pv * dec + acc[mi][nj][r] + sws;
        const float g = sigmoidf_(acc[mi][2 + nj][r] + bg);
        S[(size_t)row * 256 + cg] = f2bf(sp);
        G[(size_t)row * 256 + cg] = f2bf(g);
      }
  }
}

// ---------------------------------------------------------------------------
// GEMM2 + elementwise: P = S @ wpp^T; h = (S + pstr*tanh(P+spp)) * G * gst
__global__ __launch_bounds__(256) void gemm2h_k(const short* __restrict__ S,
                                                const short* __restrict__ G,
                                                const short* __restrict__ Wpp,
                                                const float* __restrict__ vecs,
                                                short* __restrict__ H,
                                                float* __restrict__ out) {
  __shared__ short As[2][4096];
  __shared__ short Bs[2][4096];
  const int tid = (int)threadIdx.x, lane = tid & 63, w = tid >> 6;
  const int wr = w >> 1, wc = w & 1;
  int bid = (int)blockIdx.x;
  bid = (bid & 7) * 32 + (bid >> 3);           // 256 % 8 == 0
  const int m0 = (bid >> 1) * 128, n0 = (bid & 1) * 128;
  const int b = m0 >> 11;
  const short* gA = S + (size_t)m0 * 256;
  const short* gB = Wpp + (size_t)n0 * 256;

  f32x4 acc[4][4];
#pragma unroll
  for (int mi = 0; mi < 4; ++mi)
#pragma unroll
    for (int ni = 0; ni < 4; ++ni)
#pragma unroll
      for (int r = 0; r < 4; ++r) acc[mi][ni][r] = 0.f;

  stage_tile(gA, gB, As[0], Bs[0], 256, 256, w, lane);
  __syncthreads();
  const int arow = lane & 15, ag = lane >> 4;
#pragma unroll 1
  for (int t = 0; t < 8; ++t) {
    if (t < 7)
      stage_tile(gA + (t + 1) * 32, gB + (t + 1) * 32,
                 As[(t + 1) & 1], Bs[(t + 1) & 1], 256, 256, w, lane);
    kstep(As[t & 1], Bs[t & 1], wr, wc, arow, ag, acc);
    __syncthreads();
  }
#pragma unroll
  for (int mi = 0; mi < 4; ++mi)
#pragma unroll
    for (int ni = 0; ni < 4; ++ni) {
      const int col = n0 + wc * 64 + ni * 16 + (lane & 15);
      const float spp  = vecs[2 * 2048 + b * 256 + col];
      const float pstr = vecs[3 * 2048 + b * 256 + col];
      const float gst  = vecs[4 * 2048 + b * 256 + col];
#pragma unroll
      for (int r = 0; r < 4; ++r) {
        const int row = m0 + wr * 64 + mi * 16 + (lane >> 4) * 4 + r;
        const float pv = tanhf(acc[mi][ni][r] + spp);
        const float sp = bf2f(S[(size_t)row * 256 + col]);
        const float h = (sp + pstr * pv) * bf2f(G[(size_t)row * 256 + col]) * gst;
        H[(size_t)row * 256 + col] = f2bf(h);
        if ((row & 2047) == 2047) out[16777216 + b * 256 + col] = h;
      }
    }
}

// ---------------------------------------------------------------------------
// GEMM3: out[16384][1024] f32 = H @ wout^T. 128x256 tile, K=256 -> 8 k-steps.
// 4 waves in 2x2; wave = 64 rows x 128 cols (acc[4][8]): 32 MFMA / 12 reads
// per k-step. grid = 128 m x 4 n = 512 blocks.
__global__ __launch_bounds__(256) void gemm3_k(const short* __restrict__ H,
                                               const short* __restrict__ Wout,
                                               float* __restrict__ out) {
  __shared__ short As[2][4096];   // [128][32]
  __shared__ short Bs[2][8192];   // [256][32]
  const int tid = (int)threadIdx.x, lane = tid & 63, w = tid >> 6;
  const int wr = w >> 1, wc = w & 1;
  int bid = (int)blockIdx.x;
  bid = (bid & 7) * 64 + (bid >> 3);           // XCD swizzle (512 % 8 == 0)
  const int m0 = (bid >> 2) * 128, n0 = (bid & 3) * 256;
  const short* gA = H + (size_t)m0 * 256;
  const short* gB = Wout + (size_t)n0 * 256;

  f32x4 acc[4][8];
#pragma unroll
  for (int mi = 0; mi < 4; ++mi)
#pragma unroll
    for (int ni = 0; ni < 8; ++ni)
#pragma unroll
      for (int r = 0; r < 4; ++r) acc[mi][ni][r] = 0.f;

  // stage: A 512 granules (2/thread), B 1024 granules (4/thread)
#define STAGE3(buf, t)                                                        \
  {                                                                           \
    _Pragma("unroll")                                                         \
    for (int j = 0; j < 2; ++j) {                                             \
      const int g = j * 256 + tid;                                            \
      gl16(gA + (size_t)(g >> 2) * 256 + (t) * 32 + (g & 3) * 8,              \
           As[buf] + (j * 256 + w * 64) * 8);                                 \
    }                                                                         \
    _Pragma("unroll")                                                         \
    for (int j = 0; j < 4; ++j) {                                             \
      const int g = j * 256 + tid;                                            \
      gl16(gB + (size_t)(g >> 2) * 256 + (t) * 32 + (g & 3) * 8,              \
           Bs[buf] + (j * 256 + w * 64) * 8);                                 \
    }                                                                         \
  }

  STAGE3(0, 0);
  __syncthreads();
  const int arow = lane & 15, ag = lane >> 4;
#pragma unroll 1
  for (int t = 0; t < 8; ++t) {
    if (t < 7) STAGE3((t + 1) & 1, t + 1);
    const short* Asb = As[t & 1];
    const short* Bsb = Bs[t & 1];
    bf16x8 af[4], bfv[8];
#pragma unroll
    for (int mi = 0; mi < 4; ++mi)
      af[mi] = *(const bf16x8*)(Asb + (wr * 64 + mi * 16 + arow) * 32 + ag * 8);
#pragma unroll
    for (int ni = 0; ni < 8; ++ni)
      bfv[ni] = *(const bf16x8*)(Bsb + (wc * 128 + ni * 16 + arow) * 32 + ag * 8);
#pragma unroll
    for (int mi = 0; mi < 4; ++mi)
#pragma unroll
      for (int ni = 0; ni < 8; ++ni)
        acc[mi][ni] = __builtin_amdgcn_mfma_f32_16x16x32_bf16(af[mi], bfv[ni], acc[mi][ni], 0, 0, 0);
    __syncthreads();
  }
#undef STAGE3

#pragma unroll
  for (int mi = 0; mi < 4; ++mi)
#pragma unroll
    for (int ni = 0; ni < 8; ++ni) {
      const int col = n0 + wc * 128 + ni * 16 + (lane & 15);
#pragma unroll
      for (int r = 0; r < 4; ++r) {
        const int row = m0 + wr * 64 + mi * 16 + (lane >> 4) * 4 + r;
        out[(size_t)row * 1024 + col] = acc[mi][ni][r];
      }
    }
}

// ---------------------------------------------------------------------------
extern "C" void kernel_launch(void* const* d_in, const int* in_sizes, int n_in,
                              void* d_out, int out_size, void* d_ws, size_t ws_size,
                              hipStream_t stream) {
  (void)in_sizes; (void)n_in; (void)out_size; (void)ws_size;
  const float* x      = (const float*)d_in[0];
  const float* prev   = (const float*)d_in[1];
  const float* W_in   = (const float*)d_in[2];
  const float* W_x    = (const float*)d_in[3];
  const float* W_s    = (const float*)d_in[4];
  const float* W_out  = (const float*)d_in[5];
  const float* W_gx   = (const float*)d_in[6];
  const float* b_gx   = (const float*)d_in[7];
  const float* W_gs   = (const float*)d_in[8];
  const float* b_gs   = (const float*)d_in[9];
  const float* W_dc   = (const float*)d_in[10];
  const float* b_dc   = (const float*)d_in[11];
  const float* W_pp   = (const float*)d_in[12];
  const float* b_pp   = (const float*)d_in[13];
  const float* W_pg   = (const float*)d_in[14];
  const float* b_pg   = (const float*)d_in[15];

  char* ws = (char*)d_ws;
  short* S    = (short*)(ws + OFF_S);
  short* G    = (short*)(ws + OFF_G);
  short* xbf  = (short*)(ws + OFF_XBF);
  short* H    = (short*)(ws + OFF_XBF);   // aliases xbf (dead after gemm1)
  short* wcat = (short*)(ws + OFF_WCAT);
  short* wpp  = (short*)(ws + OFF_WPP);
  short* wout = (short*)(ws + OFF_WOUT);
  float* vecs = (float*)(ws + OFF_VEC);
  float* out  = (float*)d_out;

  prep_all_k<<<12704, 256, 0, stream>>>(x, xbf, W_in, W_x, W_gx, W_dc, W_pp, W_out,
                                        wcat, wpp, wout, prev, W_s, b_dc, b_pp,
                                        W_pg, b_pg, W_gs, b_gs, vecs);
  gemm1sg_k<<<1024, 256, 0, stream>>>(xbf, wcat, prev, b_gx, vecs, S, G);
  gemm2h_k<<<256, 256, 0, stream>>>(S, G, wpp, vecs, H, out);
  gemm3_k<<<512, 256, 0, stream>>>(H, wout, out);
}

// Round 11
// 104.724 us; speedup vs baseline: 1.1411x; 1.0547x over previous
//
#include <hip/hip_runtime.h>
#include <hip/hip_bf16.h>
#include <math.h>

// ---------------------------------------------------------------------------
// GatedTinyMambaLayer: B=8, T=2048, DM=1024, DS=256
// s_prev = broadcast(prev_state) -> per-batch [8,256] precomputes.
// Pipeline (4 launches): prep_all (cvt_x + weight prep + state GEMVs) ->
// gemm1sg (128x96 tile, m97 single-barrier dbuf loop; epilogue computes S,G)
// -> gemm2h (64x128) -> gemm3 (64x256).
// wcat row order: 8 groups of 96 rows: group g = {W_in+W_x[g*32..+31],
// W_gx[g*32..+31], W_dc[g*32..+31]}.
// ---------------------------------------------------------------------------

typedef __attribute__((ext_vector_type(4)))  float f32x4;
typedef __attribute__((ext_vector_type(8)))  short bf16x8;

#define DEV static __device__ __forceinline__

DEV float bf2f(short u) {
  union { float f; unsigned i; } v; v.i = ((unsigned)(unsigned short)u) << 16; return v.f;
}
DEV short f2bf(float f) {  // round-to-nearest-even
  union { float f; unsigned i; } v; v.f = f;
  unsigned x = v.i;
  return (short)((x + 0x7fffu + ((x >> 16) & 1u)) >> 16);
}
DEV unsigned pk_bf16(float lo, float hi) {  // -> v_cvt_pk_bf16_f32
  __hip_bfloat162 h = __float22bfloat162_rn(make_float2(lo, hi));
  return *(unsigned*)&h;
}
DEV float sigmoidf_(float x) { return 1.f / (1.f + expf(-x)); }

DEV void gl16(const void* g, void* l) {
  __builtin_amdgcn_global_load_lds(
      (const __attribute__((address_space(1))) void*)(g),
      (__attribute__((address_space(3))) void*)(l), 16, 0, 0);
}

// ---- workspace layout (bytes) ---------------------------------------------
static const size_t OFF_S    = 0;                   // bf16 [16384][256]
static const size_t OFF_G    = 8388608;             // bf16 [16384][256]
static const size_t OFF_XBF  = 25165824;            // bf16 [16384][1024]; H aliases (dead after gemm1)
static const size_t OFF_WCAT = OFF_XBF + 33554432;  // bf16 [768][1024] (96-row groups)
static const size_t OFF_WPP  = OFF_WCAT + 1572864;  // bf16 [256][256]  (W_pp[:, :256])
static const size_t OFF_WOUT = OFF_WPP + 131072;    // bf16 [1024][256]
static const size_t OFF_VEC  = OFF_WOUT + 524288;   // f32 [5][2048]: sdc,sws,spp,pstr,gst

// ---------------------------------------------------------------------------
// prep_all: blocks [0,8192) cvt_x ; [8192,12544) prep_w ; [12544,12704) state
__global__ __launch_bounds__(256, 1) void prep_all_k(
    const float* __restrict__ x, short* __restrict__ xbf,
    const float* __restrict__ W_in, const float* __restrict__ W_x,
    const float* __restrict__ W_gx, const float* __restrict__ W_dc,
    const float* __restrict__ W_pp, const float* __restrict__ W_out,
    short* __restrict__ wcat, short* __restrict__ wpp, short* __restrict__ wout,
    const float* __restrict__ prev, const float* __restrict__ Ws,
    const float* __restrict__ bdc, const float* __restrict__ bpp,
    const float* __restrict__ Wpg, const float* __restrict__ bpg,
    const float* __restrict__ Wgs, const float* __restrict__ bgs,
    float* __restrict__ vecs) {
  const int bid = (int)blockIdx.x, tid = (int)threadIdx.x;
  if (bid < 8192) {  // ---- x f32 -> bf16, 8 elems/thread
    const size_t i = ((size_t)bid * 256 + tid) * 8;
    const float4 a = *(const float4*)(x + i);
    const float4 b = *(const float4*)(x + i + 4);
    uint4 o;
    o.x = pk_bf16(a.x, a.y); o.y = pk_bf16(a.z, a.w);
    o.z = pk_bf16(b.x, b.y); o.w = pk_bf16(b.z, b.w);
    *(uint4*)(xbf + i) = o;
  } else if (bid < 12544) {  // ---- weight prep
    const int idx = (bid - 8192) * 256 + tid;
    const int N_WCAT = 768 * 1024, N_WPP = 256 * 256;
    if (idx < N_WCAT) {
      const int r = idx >> 10, k = idx & 1023;
      const int g = r / 96, j = r % 96;
      float v;
      if (j < 32)      v = W_in[(g * 32 + j) * 1024 + k] + W_x[(g * 32 + j) * 1024 + k];
      else if (j < 64) v = W_gx[(g * 32 + j - 32) * 1024 + k];
      else             v = W_dc[(g * 32 + j - 64) * 1280 + k];
      wcat[idx] = f2bf(v);
    } else if (idx < N_WCAT + N_WPP) {
      const int j = idx - N_WCAT, o = j >> 8, k = j & 255;
      wpp[j] = f2bf(W_pp[o * 512 + k]);          // W_pp[:, :256]
    } else {
      const int j = idx - N_WCAT - N_WPP, o = j >> 8, k = j & 255;
      wout[j] = f2bf(W_out[o * 256 + k]);
    }
  } else {  // ---- per-batch state GEMVs (coalesced, butterfly reduce)
    const int sb = bid - 12544;
    const int b = sb / 20, rem = sb % 20, m = rem >> 2, oq = rem & 3;
    const int lane = tid & 63, w = tid >> 6;
    const float4 sv = *(const float4*)(prev + b * 256 + lane * 4);
    const float* Wb; const float* bias; int stride, off;
    if (m == 0)      { Wb = W_dc; stride = 1280; off = 1024; bias = bdc; }
    else if (m == 1) { Wb = Ws;   stride = 256;  off = 0;    bias = nullptr; }
    else if (m == 2) { Wb = W_pp; stride = 512;  off = 256;  bias = bpp; }
    else if (m == 3) { Wb = Wpg;  stride = 256;  off = 0;    bias = bpg; }
    else             { Wb = Wgs;  stride = 256;  off = 0;    bias = bgs; }
    const int o0 = oq * 64 + w * 16;
#pragma unroll 4
    for (int i = 0; i < 16; ++i) {
      const int o = o0 + i;
      const float4 wv = *(const float4*)(Wb + (size_t)o * stride + off + lane * 4);
      float p = wv.x * sv.x + wv.y * sv.y + wv.z * sv.z + wv.w * sv.w;
#pragma unroll
      for (int d = 32; d >= 1; d >>= 1) p += __shfl_xor(p, d, 64);
      if (lane == 0) {
        float r = (m == 1) ? 0.5f * p : p + bias[o];
        if (m >= 3) r = sigmoidf_(r);
        vecs[m * 2048 + b * 256 + o] = r;
      }
    }
  }
}

// ---------------------------------------------------------------------------
// GEMM1+SG: 128x96 tile, grid = 128 m-tiles x 8 col-groups = 1024 blocks
// (4 blocks/CU). m97 single-barrier dbuf loop. 4 waves, each 32 rows x 96
// cols (acc[2][6]). K=1024.
// Epilogue: S = prev*exp(-.05*sig(dc+sdc)) + ix + sws ; G = sig(gx+bgx).
__global__ __launch_bounds__(256) void gemm1sg_k(const short* __restrict__ A,
                                                 const short* __restrict__ Bm,
                                                 const float* __restrict__ prev,
                                                 const float* __restrict__ bgx,
                                                 const float* __restrict__ vecs,
                                                 short* __restrict__ S,
                                                 short* __restrict__ G) {
  __shared__ short As[2][4096];    // [128][32]
  __shared__ short Bs[2][3072];    // [96][32]
  const int tid = (int)threadIdx.x, lane = tid & 63, w = tid >> 6;
  int bid = (int)blockIdx.x;
  bid = (bid & 7) * 128 + (bid >> 3);          // XCD swizzle (1024 % 8 == 0)
  const int mt = bid >> 3, ntg = bid & 7;
  const int m0 = mt * 128, b = m0 >> 11;
  const short* gA = A + (size_t)m0 * 1024;
  const short* gB = Bm + (size_t)(ntg * 96) * 1024;
  const int rsub = lane >> 2, kc = (lane & 3) * 8;

  f32x4 acc[2][6];
#pragma unroll
  for (int mi = 0; mi < 2; ++mi)
#pragma unroll
    for (int ni = 0; ni < 6; ++ni)
#pragma unroll
      for (int r = 0; r < 4; ++r) acc[mi][ni][r] = 0.f;

  // staging: A 512 granules (2/thread); B 384 granules (1/thread + half on w<2)
#define STAGE1(buf, t)                                                        \
  {                                                                           \
    _Pragma("unroll")                                                         \
    for (int j = 0; j < 2; ++j) {                                             \
      const int seg = w * 2 + j;                                              \
      gl16(gA + (size_t)(seg * 16 + rsub) * 1024 + (t) * 32 + kc,             \
           As[buf] + seg * 512);                                              \
    }                                                                         \
    {                                                                         \
      const int Gr = w * 64 + lane;                                           \
      gl16(gB + (size_t)(Gr >> 2) * 1024 + (t) * 32 + ((Gr & 3) * 8),         \
           Bs[buf] + w * 512);                                                \
    }                                                                         \
    if (w < 2) {                                                              \
      const int Gr = 256 + w * 64 + lane;                                     \
      gl16(gB + (size_t)(Gr >> 2) * 1024 + (t) * 32 + ((Gr & 3) * 8),         \
           Bs[buf] + 2048 + w * 512);                                         \
    }                                                                         \
  }

  STAGE1(0, 0);
  __syncthreads();
  const int arow = lane & 15, ag = lane >> 4;
#pragma unroll 1
  for (int t = 0; t < 32; ++t) {
    if (t < 31) STAGE1((t + 1) & 1, t + 1);
    const short* Asb = As[t & 1];
    const short* Bsb = Bs[t & 1];
    bf16x8 af[2];
#pragma unroll
    for (int mi = 0; mi < 2; ++mi)
      af[mi] = *(const bf16x8*)(Asb + (w * 32 + mi * 16 + arow) * 32 + ag * 8);
#pragma unroll
    for (int ni = 0; ni < 6; ++ni) {
      const bf16x8 bf = *(const bf16x8*)(Bsb + (ni * 16 + arow) * 32 + ag * 8);
#pragma unroll
      for (int mi = 0; mi < 2; ++mi)
        acc[mi][ni] = __builtin_amdgcn_mfma_f32_16x16x32_bf16(af[mi], bf, acc[mi][ni], 0, 0, 0);
    }
    __syncthreads();
  }
#undef STAGE1

  // epilogue: B-rows 0..31 = ix, 32..63 = gx, 64..95 = dc (within group ntg)
  const int quad = lane >> 4;
#pragma unroll
  for (int nj = 0; nj < 2; ++nj) {
    const int cg = ntg * 32 + nj * 16 + arow;
    const float sdc = vecs[0 * 2048 + b * 256 + cg];
    const float sws = vecs[1 * 2048 + b * 256 + cg];
    const float pv  = prev[b * 256 + cg];
    const float bg  = bgx[cg];
#pragma unroll
    for (int mi = 0; mi < 2; ++mi)
#pragma unroll
      for (int r = 0; r < 4; ++r) {
        const int row = m0 + w * 32 + mi * 16 + quad * 4 + r;
        const float dec = expf(-0.05f * sigmoidf_(acc[mi][4 + nj][r] + sdc));
        const float sp = pv * dec + acc[mi][nj][r] + sws;
        const float g = sigmoidf_(acc[mi][2 + nj][r] + bg);
        S[(size_t)row * 256 + cg] = f2bf(sp);
        G[(size_t)row * 256 + cg] = f2bf(g);
      }
  }
}

// ---------------------------------------------------------------------------
// GEMM2 + elementwise: P = S @ wpp^T; h = (S + pstr*tanh(P+spp)) * G * gst
// 64x128 tile, grid = 256 m x 2 n = 512 blocks (2/CU). Wave = 32r x 64c.
__global__ __launch_bounds__(256) void gemm2h_k(const short* __restrict__ S,
                                                const short* __restrict__ G,
                                                const short* __restrict__ Wpp,
                                                const float* __restrict__ vecs,
                                                short* __restrict__ H,
                                                float* __restrict__ out) {
  __shared__ short As[2][2048];   // [64][32]
  __shared__ short Bs[2][4096];   // [128][32]
  const int tid = (int)threadIdx.x, lane = tid & 63, w = tid >> 6;
  const int wr = w >> 1, wc = w & 1;
  int bid = (int)blockIdx.x;
  bid = (bid & 7) * 64 + (bid >> 3);           // XCD swizzle (512 % 8 == 0)
  const int m0 = (bid >> 1) * 64, n0 = (bid & 1) * 128;
  const int b = m0 >> 11;
  const short* gA = S + (size_t)m0 * 256;
  const short* gB = Wpp + (size_t)n0 * 256;

  f32x4 acc[2][4];
#pragma unroll
  for (int mi = 0; mi < 2; ++mi)
#pragma unroll
    for (int ni = 0; ni < 4; ++ni)
#pragma unroll
      for (int r = 0; r < 4; ++r) acc[mi][ni][r] = 0.f;

  // stage: A 256 granules (1/thread), B 512 granules (2/thread)
#define STAGE2(buf, t)                                                        \
  {                                                                           \
    {                                                                         \
      const int g = tid;                                                      \
      gl16(gA + (size_t)(g >> 2) * 256 + (t) * 32 + (g & 3) * 8,              \
           As[buf] + w * 512);                                                \
    }                                                                         \
    _Pragma("unroll")                                                         \
    for (int j = 0; j < 2; ++j) {                                             \
      const int g = j * 256 + tid;                                            \
      gl16(gB + (size_t)(g >> 2) * 256 + (t) * 32 + (g & 3) * 8,              \
           Bs[buf] + (j * 256 + w * 64) * 8);                                 \
    }                                                                         \
  }

  STAGE2(0, 0);
  __syncthreads();
  const int arow = lane & 15, ag = lane >> 4;
#pragma unroll 1
  for (int t = 0; t < 8; ++t) {
    if (t < 7) STAGE2((t + 1) & 1, t + 1);
    const short* Asb = As[t & 1];
    const short* Bsb = Bs[t & 1];
    bf16x8 af[2], bfv[4];
#pragma unroll
    for (int mi = 0; mi < 2; ++mi)
      af[mi] = *(const bf16x8*)(Asb + (wr * 32 + mi * 16 + arow) * 32 + ag * 8);
#pragma unroll
    for (int ni = 0; ni < 4; ++ni)
      bfv[ni] = *(const bf16x8*)(Bsb + (wc * 64 + ni * 16 + arow) * 32 + ag * 8);
#pragma unroll
    for (int mi = 0; mi < 2; ++mi)
#pragma unroll
      for (int ni = 0; ni < 4; ++ni)
        acc[mi][ni] = __builtin_amdgcn_mfma_f32_16x16x32_bf16(af[mi], bfv[ni], acc[mi][ni], 0, 0, 0);
    __syncthreads();
  }
#undef STAGE2

#pragma unroll
  for (int mi = 0; mi < 2; ++mi)
#pragma unroll
    for (int ni = 0; ni < 4; ++ni) {
      const int col = n0 + wc * 64 + ni * 16 + (lane & 15);
      const float spp  = vecs[2 * 2048 + b * 256 + col];
      const float pstr = vecs[3 * 2048 + b * 256 + col];
      const float gst  = vecs[4 * 2048 + b * 256 + col];
#pragma unroll
      for (int r = 0; r < 4; ++r) {
        const int row = m0 + wr * 32 + mi * 16 + (lane >> 4) * 4 + r;
        const float pv = tanhf(acc[mi][ni][r] + spp);
        const float sp = bf2f(S[(size_t)row * 256 + col]);
        const float h = (sp + pstr * pv) * bf2f(G[(size_t)row * 256 + col]) * gst;
        H[(size_t)row * 256 + col] = f2bf(h);
        if ((row & 2047) == 2047) out[16777216 + b * 256 + col] = h;
      }
    }
}

// ---------------------------------------------------------------------------
// GEMM3: out[16384][1024] f32 = H @ wout^T. 64x256 tile, K=256 -> 8 k-steps.
// grid = 256 m x 4 n = 1024 blocks (4/CU). Wave = 32r x 128c (acc[2][8]).
__global__ __launch_bounds__(256) void gemm3_k(const short* __restrict__ H,
                                               const short* __restrict__ Wout,
                                               float* __restrict__ out) {
  __shared__ short As[2][2048];   // [64][32]
  __shared__ short Bs[2][8192];   // [256][32]
  const int tid = (int)threadIdx.x, lane = tid & 63, w = tid >> 6;
  const int wr = w >> 1, wc = w & 1;
  int bid = (int)blockIdx.x;
  bid = (bid & 7) * 128 + (bid >> 3);          // XCD swizzle (1024 % 8 == 0)
  const int m0 = (bid >> 2) * 64, n0 = (bid & 3) * 256;
  const short* gA = H + (size_t)m0 * 256;
  const short* gB = Wout + (size_t)n0 * 256;

  f32x4 acc[2][8];
#pragma unroll
  for (int mi = 0; mi < 2; ++mi)
#pragma unroll
    for (int ni = 0; ni < 8; ++ni)
#pragma unroll
      for (int r = 0; r < 4; ++r) acc[mi][ni][r] = 0.f;

  // stage: A 256 granules (1/thread), B 1024 granules (4/thread)
#define STAGE3(buf, t)                                                        \
  {                                                                           \
    {                                                                         \
      const int g = tid;                                                      \
      gl16(gA + (size_t)(g >> 2) * 256 + (t) * 32 + (g & 3) * 8,              \
           As[buf] + w * 512);                                                \
    }                                                                         \
    _Pragma("unroll")                                                         \
    for (int j = 0; j < 4; ++j) {                                             \
      const int g = j * 256 + tid;                                            \
      gl16(gB + (size_t)(g >> 2) * 256 + (t) * 32 + (g & 3) * 8,              \
           Bs[buf] + (j * 256 + w * 64) * 8);                                 \
    }                                                                         \
  }

  STAGE3(0, 0);
  __syncthreads();
  const int arow = lane & 15, ag = lane >> 4;
#pragma unroll 1
  for (int t = 0; t < 8; ++t) {
    if (t < 7) STAGE3((t + 1) & 1, t + 1);
    const short* Asb = As[t & 1];
    const short* Bsb = Bs[t & 1];
    bf16x8 af[2], bfv[8];
#pragma unroll
    for (int mi = 0; mi < 2; ++mi)
      af[mi] = *(const bf16x8*)(Asb + (wr * 32 + mi * 16 + arow) * 32 + ag * 8);
#pragma unroll
    for (int ni = 0; ni < 8; ++ni)
      bfv[ni] = *(const bf16x8*)(Bsb + (wc * 128 + ni * 16 + arow) * 32 + ag * 8);
#pragma unroll
    for (int mi = 0; mi < 2; ++mi)
#pragma unroll
      for (int ni = 0; ni < 8; ++ni)
        acc[mi][ni] = __builtin_amdgcn_mfma_f32_16x16x32_bf16(af[mi], bfv[ni], acc[mi][ni], 0, 0, 0);
    __syncthreads();
  }
#undef STAGE3

#pragma unroll
  for (int mi = 0; mi < 2; ++mi)
#pragma unroll
    for (int ni = 0; ni < 8; ++ni) {
      const int col = n0 + wc * 128 + ni * 16 + (lane & 15);
#pragma unroll
      for (int r = 0; r < 4; ++r) {
        const int row = m0 + wr * 32 + mi * 16 + (lane >> 4) * 4 + r;
        out[(size_t)row * 1024 + col] = acc[mi][ni][r];
      }
    }
}

// ---------------------------------------------------------------------------
extern "C" void kernel_launch(void* const* d_in, const int* in_sizes, int n_in,
                              void* d_out, int out_size, void* d_ws, size_t ws_size,
                              hipStream_t stream) {
  (void)in_sizes; (void)n_in; (void)out_size; (void)ws_size;
  const float* x      = (const float*)d_in[0];
  const float* prev   = (const float*)d_in[1];
  const float* W_in   = (const float*)d_in[2];
  const float* W_x    = (const float*)d_in[3];
  const float* W_s    = (const float*)d_in[4];
  const float* W_out  = (const float*)d_in[5];
  const float* W_gx   = (const float*)d_in[6];
  const float* b_gx   = (const float*)d_in[7];
  const float* W_gs   = (const float*)d_in[8];
  const float* b_gs   = (const float*)d_in[9];
  const float* W_dc   = (const float*)d_in[10];
  const float* b_dc   = (const float*)d_in[11];
  const float* W_pp   = (const float*)d_in[12];
  const float* b_pp   = (const float*)d_in[13];
  const float* W_pg   = (const float*)d_in[14];
  const float* b_pg   = (const float*)d_in[15];

  char* ws = (char*)d_ws;
  short* S    = (short*)(ws + OFF_S);
  short* G    = (short*)(ws + OFF_G);
  short* xbf  = (short*)(ws + OFF_XBF);
  short* H    = (short*)(ws + OFF_XBF);   // aliases xbf (dead after gemm1)
  short* wcat = (short*)(ws + OFF_WCAT);
  short* wpp  = (short*)(ws + OFF_WPP);
  short* wout = (short*)(ws + OFF_WOUT);
  float* vecs = (float*)(ws + OFF_VEC);
  float* out  = (float*)d_out;

  prep_all_k<<<12704, 256, 0, stream>>>(x, xbf, W_in, W_x, W_gx, W_dc, W_pp, W_out,
                                        wcat, wpp, wout, prev, W_s, b_dc, b_pp,
                                        W_pg, b_pg, W_gs, b_gs, vecs);
  gemm1sg_k<<<1024, 256, 0, stream>>>(xbf, wcat, prev, b_gx, vecs, S, G);
  gemm2h_k<<<512, 256, 0, stream>>>(S, G, wpp, vecs, H, out);
  gemm3_k<<<1024, 256, 0, stream>>>(H, wout, out);
}